// Round 5
// baseline (60.910 us; speedup 1.0000x reference)
//
#include <hip/hip_runtime.h>

#define Nn  2048
#define Aa  256
#define Cc  100
#define LAT 128
#define BN_EPS 1e-5f

// ws layout in floats (everything fully overwritten each call -> no zeroing)
#define OFF_HB   0                         // h bf16 [2048][128] = 131072 floats
#define OFF_SUMS (OFF_HB + Nn*LAT/2)       // 128 blocks * 256 f32
#define OFF_SP   (OFF_SUMS + 128*256)      // Spart [2][100][100] f32
#define OFF_CTR  (OFF_SP + 2*Cc*Cc)        // 1 uint

typedef __attribute__((ext_vector_type(8))) short bf16x8;
typedef __attribute__((ext_vector_type(4))) float f32x4;

__device__ __forceinline__ short f2bf(float f) {
    unsigned u = __float_as_uint(f);
    u = (u + 0x7FFFu + ((u >> 16) & 1u)) >> 16;
    return (short)u;
}
__device__ __forceinline__ float bf2f(short h) {
    return __uint_as_float(((unsigned)(unsigned short)h) << 16);
}

// ---------------- A: h = s @ W1^T + b1 (bf16 out) + per-block stats -----------
// grid 128: block owns 16 rows x N=128; 4 waves, wave w cols [w*32, w*32+32)
__global__ __launch_bounds__(256) void k1_mfma(
    const float* __restrict__ s, const float* __restrict__ W1,
    const float* __restrict__ b1, short* __restrict__ hB,
    float* __restrict__ sums, unsigned* __restrict__ ctr)
{
    if (blockIdx.x == 0 && threadIdx.x == 0) *ctr = 0;  // reset barrier for kernel B

    const int t = threadIdx.x;
    const int w = t >> 6, l = t & 63, il = l & 15, q = l >> 4;
    const int row0 = blockIdx.x * 16;
    const int colw = w * 32;

    f32x4 acc[2];
    acc[0] = (f32x4){0.f,0.f,0.f,0.f};
    acc[1] = (f32x4){0.f,0.f,0.f,0.f};

    const float* arow = s  + (size_t)(row0 + il) * Aa;
    const float* bp0  = W1 + (size_t)(colw + il) * Aa;
    const float* bp1  = W1 + (size_t)(colw + 16 + il) * Aa;

#pragma unroll
    for (int ks = 0; ks < 8; ks++) {
        const int k0 = ks * 32 + q * 8;
        float4 u0 = *(const float4*)&arow[k0];
        float4 u1 = *(const float4*)&arow[k0 + 4];
        bf16x8 am;
        am[0]=f2bf(u0.x); am[1]=f2bf(u0.y); am[2]=f2bf(u0.z); am[3]=f2bf(u0.w);
        am[4]=f2bf(u1.x); am[5]=f2bf(u1.y); am[6]=f2bf(u1.z); am[7]=f2bf(u1.w);
        float4 v0 = *(const float4*)&bp0[k0];
        float4 v1 = *(const float4*)&bp0[k0 + 4];
        bf16x8 bm0;
        bm0[0]=f2bf(v0.x); bm0[1]=f2bf(v0.y); bm0[2]=f2bf(v0.z); bm0[3]=f2bf(v0.w);
        bm0[4]=f2bf(v1.x); bm0[5]=f2bf(v1.y); bm0[6]=f2bf(v1.z); bm0[7]=f2bf(v1.w);
        float4 x0 = *(const float4*)&bp1[k0];
        float4 x1 = *(const float4*)&bp1[k0 + 4];
        bf16x8 bm1;
        bm1[0]=f2bf(x0.x); bm1[1]=f2bf(x0.y); bm1[2]=f2bf(x0.z); bm1[3]=f2bf(x0.w);
        bm1[4]=f2bf(x1.x); bm1[5]=f2bf(x1.y); bm1[6]=f2bf(x1.z); bm1[7]=f2bf(x1.w);
        acc[0] = __builtin_amdgcn_mfma_f32_16x16x32_bf16(am, bm0, acc[0], 0, 0, 0);
        acc[1] = __builtin_amdgcn_mfma_f32_16x16x32_bf16(am, bm1, acc[1], 0, 0, 0);
    }

#pragma unroll
    for (int n = 0; n < 2; n++) {
        const int col = colw + n * 16 + il;
        const float bias = b1[col];
        float s1 = 0.f, s2 = 0.f;
#pragma unroll
        for (int r = 0; r < 4; r++) {
            float v = acc[n][r] + bias;
            hB[(size_t)(row0 + q * 4 + r) * LAT + col] = f2bf(v);
            s1 += v; s2 += v * v;
        }
        s1 += __shfl_xor(s1, 16); s1 += __shfl_xor(s1, 32);
        s2 += __shfl_xor(s2, 16); s2 += __shfl_xor(s2, 32);
        if (q == 0) {
            sums[blockIdx.x * 256 + col]       = s1;
            sums[blockIdx.x * 256 + 128 + col] = s2;
        }
    }
}

// ---------------- B: fused { ks halves | k3+k4 } ------------------------------
// grid 328: bid 0..199  -> ks half (k = bid>>1, b-half = bid&1) -> Spart[nh]
//           bid 200..327 -> 16-row MLP tile: BN + GEMM1 -> LDS f -> GEMM2,
//                           spin on ctr, add coef*S gather, store out.
#define DPITCH 264     // bf16 pitch: 528 B, odd multiple of 16B
#define FPITCH 264

__global__ __launch_bounds__(256) void kB(
    const short* __restrict__ hB, const float* __restrict__ sums,
    const float* __restrict__ gamma, const float* __restrict__ beta,
    const float* __restrict__ W2, const float* __restrict__ b2,
    const float* __restrict__ Wfc, const float* __restrict__ bfc,
    const float* __restrict__ cov, const int* __restrict__ y,
    const float* __restrict__ ratio,
    float* __restrict__ Spart, unsigned* __restrict__ ctr,
    float* __restrict__ out)
{
    __shared__ __align__(16) char smem[61440];
    const int bid = blockIdx.x;
    const int t = threadIdx.x;
    const int w = t >> 6, l = t & 63, il = l & 15, q = l >> 4;

    if (bid < 200) {
        // ---------------- ks half ----------------
        short* Dlds = (short*)smem;                       // 112 x DPITCH
        float (*red)[112] = (float(*)[112])(smem + 112 * DPITCH * 2);
        const int k  = bid >> 1;
        const int nh = bid & 1;
        const float* covk = cov + (size_t)k * (Aa * Aa);

        {   // stage D = Wfc - Wfc[k] (bf16), rows >= Cc zero
            const int c4 = t & 63;
            float4 wk = *(const float4*)&Wfc[(size_t)k * Aa + c4 * 4];
#pragma unroll
            for (int j = 0; j < 28; j++) {
                int row = (t >> 6) + j * 4;
                short4 o;
                if (row < Cc) {
                    float4 v = *(const float4*)&Wfc[(size_t)row * Aa + c4 * 4];
                    o.x = f2bf(v.x - wk.x); o.y = f2bf(v.y - wk.y);
                    o.z = f2bf(v.z - wk.z); o.w = f2bf(v.w - wk.w);
                } else {
                    o.x = 0; o.y = 0; o.z = 0; o.w = 0;
                }
                *(short4*)&Dlds[row * DPITCH + c4 * 4] = o;
            }
        }
        __syncthreads();

        const int bbase = nh * 128 + w * 32;

        f32x4 acc[7][2];
#pragma unroll
        for (int m = 0; m < 7; m++) {
            acc[m][0] = (f32x4){0.f,0.f,0.f,0.f};
            acc[m][1] = (f32x4){0.f,0.f,0.f,0.f};
        }

        const float* brow0 = covk + (size_t)(bbase + il) * Aa;
        const float* brow1 = covk + (size_t)(bbase + 16 + il) * Aa;

#pragma unroll
        for (int sgk = 0; sgk < 8; sgk++) {
            const int a0 = sgk * 32 + q * 8;
            bf16x8 bm0, bm1;
            {
                float4 u0 = *(const float4*)&brow0[a0];
                float4 u1 = *(const float4*)&brow0[a0 + 4];
                bm0[0]=f2bf(u0.x); bm0[1]=f2bf(u0.y); bm0[2]=f2bf(u0.z); bm0[3]=f2bf(u0.w);
                bm0[4]=f2bf(u1.x); bm0[5]=f2bf(u1.y); bm0[6]=f2bf(u1.z); bm0[7]=f2bf(u1.w);
                float4 v0 = *(const float4*)&brow1[a0];
                float4 v1 = *(const float4*)&brow1[a0 + 4];
                bm1[0]=f2bf(v0.x); bm1[1]=f2bf(v0.y); bm1[2]=f2bf(v0.z); bm1[3]=f2bf(v0.w);
                bm1[4]=f2bf(v1.x); bm1[5]=f2bf(v1.y); bm1[6]=f2bf(v1.z); bm1[7]=f2bf(v1.w);
            }
#pragma unroll
            for (int m = 0; m < 7; m++) {
                bf16x8 am = *(bf16x8*)&Dlds[(m * 16 + il) * DPITCH + a0];
                acc[m][0] = __builtin_amdgcn_mfma_f32_16x16x32_bf16(am, bm0, acc[m][0], 0, 0, 0);
                acc[m][1] = __builtin_amdgcn_mfma_f32_16x16x32_bf16(am, bm1, acc[m][1], 0, 0, 0);
            }
        }

#pragma unroll
        for (int m = 0; m < 7; m++) {
            float sacc[4] = {0.f, 0.f, 0.f, 0.f};
#pragma unroll
            for (int nf = 0; nf < 2; nf++) {
                int bcol = bbase + nf * 16 + il;
#pragma unroll
                for (int r = 0; r < 4; r++) {
                    int crow = m * 16 + q * 4 + r;
                    float dv = bf2f(Dlds[crow * DPITCH + bcol]);
                    sacc[r] = fmaf(dv, acc[m][nf][r], sacc[r]);
                }
            }
#pragma unroll
            for (int r = 0; r < 4; r++) {
                float v = sacc[r];
                v += __shfl_xor(v, 1);
                v += __shfl_xor(v, 2);
                v += __shfl_xor(v, 4);
                v += __shfl_xor(v, 8);
                if (il == 0) red[w][m * 16 + q * 4 + r] = v;
            }
        }
        __syncthreads();
        if (t < Cc)
            Spart[nh * (Cc * Cc) + k * Cc + t] =
                red[0][t] + red[1][t] + red[2][t] + red[3][t];
        __threadfence();                 // release own stores device-wide
        __syncthreads();                 // all threads' fences done
        if (t == 0) atomicAdd(ctr, 1u);  // signal
    } else {
        // ---------------- fused k3+k4 tile ----------------
        const int bid2 = bid - 200;
        const int row0 = bid2 * 16;
        float* scL = (float*)smem;           // 128
        float* shL = scL + 128;              // 128
        short* fLDS = (short*)(smem + 1024); // 16 x FPITCH

        if (t < 128) {
            float a1 = 0.f, a2 = 0.f;
#pragma unroll 8
            for (int b = 0; b < 128; b++) {
                a1 += sums[b * 256 + t];
                a2 += sums[b * 256 + 128 + t];
            }
            float mu  = a1 * (1.0f / Nn);
            float var = a2 * (1.0f / Nn) - mu * mu;
            float inv = rsqrtf(var + BN_EPS);
            float sc  = gamma[t] * inv;
            scL[t] = sc;
            shL[t] = beta[t] - mu * sc;
        }
        __syncthreads();

        // ---- GEMM1: f_tile = relu(bn(h_tile) @ W2^T + b2), cols w*64..+64 ----
        f32x4 acc3[4];
#pragma unroll
        for (int n = 0; n < 4; n++) acc3[n] = (f32x4){0.f,0.f,0.f,0.f};

        const short* arow = hB + (size_t)(row0 + il) * LAT;
#pragma unroll
        for (int ks = 0; ks < 4; ks++) {
            const int k0 = ks * 32 + q * 8;
            bf16x8 ha = *(const bf16x8*)&arow[k0];
            bf16x8 am;
#pragma unroll
            for (int j = 0; j < 8; j++) {
                float fv = fmaf(bf2f(ha[j]), scL[k0 + j], shL[k0 + j]);
                am[j] = f2bf(fmaxf(fv, 0.f));
            }
#pragma unroll
            for (int n = 0; n < 4; n++) {
                const int col = w * 64 + n * 16 + il;
                float4 v0 = *(const float4*)&W2[(size_t)col * LAT + k0];
                float4 v1 = *(const float4*)&W2[(size_t)col * LAT + k0 + 4];
                bf16x8 bm;
                bm[0]=f2bf(v0.x); bm[1]=f2bf(v0.y); bm[2]=f2bf(v0.z); bm[3]=f2bf(v0.w);
                bm[4]=f2bf(v1.x); bm[5]=f2bf(v1.y); bm[6]=f2bf(v1.z); bm[7]=f2bf(v1.w);
                acc3[n] = __builtin_amdgcn_mfma_f32_16x16x32_bf16(am, bm, acc3[n], 0, 0, 0);
            }
        }
#pragma unroll
        for (int n = 0; n < 4; n++) {
            const int col = w * 64 + n * 16 + il;
            const float bias = b2[col];
#pragma unroll
            for (int r = 0; r < 4; r++) {
                float v = fmaxf(acc3[n][r] + bias, 0.f);
                fLDS[(q * 4 + r) * FPITCH + col] = f2bf(v);
            }
        }
        __syncthreads();

        // ---- GEMM2: out_tile = f_tile @ Wfc^T, cols w*32..+32 ----
        f32x4 acc4[2];
        acc4[0] = (f32x4){0.f,0.f,0.f,0.f};
        acc4[1] = (f32x4){0.f,0.f,0.f,0.f};
#pragma unroll
        for (int ks = 0; ks < 8; ks++) {
            const int k0 = ks * 32 + q * 8;
            bf16x8 am = *(const bf16x8*)&fLDS[il * FPITCH + k0];
#pragma unroll
            for (int n = 0; n < 2; n++) {
                const int col = w * 32 + n * 16 + il;
                const int crow = col < Cc ? col : Cc - 1;  // clamp: garbage cols masked at store
                float4 v0 = *(const float4*)&Wfc[(size_t)crow * Aa + k0];
                float4 v1 = *(const float4*)&Wfc[(size_t)crow * Aa + k0 + 4];
                bf16x8 bm;
                bm[0]=f2bf(v0.x); bm[1]=f2bf(v0.y); bm[2]=f2bf(v0.z); bm[3]=f2bf(v0.w);
                bm[4]=f2bf(v1.x); bm[5]=f2bf(v1.y); bm[6]=f2bf(v1.z); bm[7]=f2bf(v1.w);
                acc4[n] = __builtin_amdgcn_mfma_f32_16x16x32_bf16(am, bm, acc4[n], 0, 0, 0);
            }
        }

        // ---- wait for all ks halves, then epilogue with S gather ----
        if (t == 0) {
            while (__hip_atomic_load(ctr, __ATOMIC_ACQUIRE, __HIP_MEMORY_SCOPE_AGENT) < 200u) {}
        }
        __syncthreads();

        const float coef = 0.5f * ratio[0];
        const int4 yv4 = *(const int4*)&y[row0 + q * 4];
        const int yr[4] = {yv4.x, yv4.y, yv4.z, yv4.w};

#pragma unroll
        for (int n = 0; n < 2; n++) {
            const int col = w * 32 + n * 16 + il;
            if (col < Cc) {
                const float bias = bfc[col];
#pragma unroll
                for (int r = 0; r < 4; r++) {
                    float sp0 = __hip_atomic_load(&Spart[yr[r] * Cc + col],
                                                  __ATOMIC_RELAXED, __HIP_MEMORY_SCOPE_AGENT);
                    float sp1 = __hip_atomic_load(&Spart[Cc * Cc + yr[r] * Cc + col],
                                                  __ATOMIC_RELAXED, __HIP_MEMORY_SCOPE_AGENT);
                    out[(size_t)(row0 + q * 4 + r) * Cc + col] =
                        acc4[n][r] + bias + coef * (sp0 + sp1);
                }
            }
        }
    }
}

extern "C" void kernel_launch(void* const* d_in, const int* in_sizes, int n_in,
                              void* d_out, int out_size, void* d_ws, size_t ws_size,
                              hipStream_t stream)
{
    const float* s     = (const float*)d_in[0];
    const int*   y     = (const int*)  d_in[1];
    const float* ratio = (const float*)d_in[2];
    const float* W1    = (const float*)d_in[3];
    const float* b1    = (const float*)d_in[4];
    const float* gamma = (const float*)d_in[5];
    const float* beta  = (const float*)d_in[6];
    const float* W2    = (const float*)d_in[7];
    const float* b2    = (const float*)d_in[8];
    const float* Wfc   = (const float*)d_in[9];
    const float* bfc   = (const float*)d_in[10];
    const float* cov   = (const float*)d_in[11];
    float* out = (float*)d_out;
    float* ws  = (float*)d_ws;

    short*    hB    = (short*)(ws + OFF_HB);
    float*    sums  = ws + OFF_SUMS;
    float*    Spart = ws + OFF_SP;
    unsigned* ctr   = (unsigned*)(ws + OFF_CTR);

    hipLaunchKernelGGL(k1_mfma, dim3(128), dim3(256), 0, stream,
                       s, W1, b1, hB, sums, ctr);
    hipLaunchKernelGGL(kB,      dim3(328), dim3(256), 0, stream,
                       hB, sums, gamma, beta, W2, b2, Wfc, bfc, cov, y, ratio,
                       Spart, ctr, out);
}

// Round 6
// 39.510 us; speedup vs baseline: 1.5416x; 1.5416x over previous
//
#include <hip/hip_runtime.h>

#define Nn  2048
#define Aa  256
#define Cc  100
#define LAT 128
#define BN_EPS 1e-5f

// ws layout in floats (everything fully overwritten each call -> no zeroing)
#define OFF_HB   0                         // h bf16 [2048][128] = 131072 floats
#define OFF_FB   (OFF_HB + Nn*LAT/2)       // f bf16 [2048][256] = 262144 floats
#define OFF_SUMS (OFF_FB + Nn*Aa/2)        // 128 blocks * 256 f32
#define OFF_S    (OFF_SUMS + 128*256)      // Cc*Cc f32

typedef __attribute__((ext_vector_type(8))) short bf16x8;
typedef __attribute__((ext_vector_type(4))) float f32x4;

__device__ __forceinline__ short f2bf(float f) {
    unsigned u = __float_as_uint(f);
    u = (u + 0x7FFFu + ((u >> 16) & 1u)) >> 16;
    return (short)u;
}
__device__ __forceinline__ float bf2f(short h) {
    return __uint_as_float(((unsigned)(unsigned short)h) << 16);
}

// ---------------- A: fused { ks (bid<100) | k1 tiles (bid>=100) } -------------
// No cross-block communication: ks writes S; k1 writes hB + per-block stats.
#define KSM 7
#define DPITCH 264     // bf16 pitch: 528 B, odd multiple of 16B

__global__ __launch_bounds__(256) void kA(
    const float* __restrict__ s, const float* __restrict__ W1,
    const float* __restrict__ b1, const float* __restrict__ Wfc,
    const float* __restrict__ cov,
    short* __restrict__ hB, float* __restrict__ sums, float* __restrict__ S)
{
    __shared__ __align__(16) char smem[112 * DPITCH * 2 + 4 * 112 * 4];
    const int bid = blockIdx.x;
    const int t = threadIdx.x;
    const int w = t >> 6, l = t & 63, il = l & 15, q = l >> 4;

    if (bid < Cc) {
        // ---------------- ks: S[k][c] = diag(D cov[k] D^T) ----------------
        short* Dlds = (short*)smem;                              // 112 x DPITCH
        float (*red)[112] = (float(*)[112])(smem + 112 * DPITCH * 2);
        const int k = bid;
        const float* covk = cov + (size_t)k * (Aa * Aa);

        {   // stage D = Wfc - Wfc[k] (bf16), rows >= Cc zero; coalesced
            const int c4 = t & 63;
            float4 wk = *(const float4*)&Wfc[(size_t)k * Aa + c4 * 4];
#pragma unroll
            for (int j = 0; j < 28; j++) {
                int row = (t >> 6) + j * 4;
                short4 o;
                if (row < Cc) {
                    float4 v = *(const float4*)&Wfc[(size_t)row * Aa + c4 * 4];
                    o.x = f2bf(v.x - wk.x); o.y = f2bf(v.y - wk.y);
                    o.z = f2bf(v.z - wk.z); o.w = f2bf(v.w - wk.w);
                } else {
                    o.x = 0; o.y = 0; o.z = 0; o.w = 0;
                }
                *(short4*)&Dlds[row * DPITCH + c4 * 4] = o;
            }
        }
        __syncthreads();

        const int bbase = w * 64;

        f32x4 acc[KSM][4];
#pragma unroll
        for (int m = 0; m < KSM; m++)
#pragma unroll
            for (int nf = 0; nf < 4; nf++)
                acc[m][nf] = (f32x4){0.f, 0.f, 0.f, 0.f};

        const float* brow0 = covk + (size_t)(bbase +  0 + il) * Aa;
        const float* brow1 = covk + (size_t)(bbase + 16 + il) * Aa;
        const float* brow2 = covk + (size_t)(bbase + 32 + il) * Aa;
        const float* brow3 = covk + (size_t)(bbase + 48 + il) * Aa;

#pragma unroll
        for (int sgk = 0; sgk < 8; sgk++) {
            const int a0 = sgk * 32 + q * 8;
            bf16x8 bm[4];
            {
                const float* br[4] = {brow0, brow1, brow2, brow3};
#pragma unroll
                for (int nf = 0; nf < 4; nf++) {
                    float4 u0 = *(const float4*)&br[nf][a0];
                    float4 u1 = *(const float4*)&br[nf][a0 + 4];
                    bm[nf][0] = f2bf(u0.x); bm[nf][1] = f2bf(u0.y);
                    bm[nf][2] = f2bf(u0.z); bm[nf][3] = f2bf(u0.w);
                    bm[nf][4] = f2bf(u1.x); bm[nf][5] = f2bf(u1.y);
                    bm[nf][6] = f2bf(u1.z); bm[nf][7] = f2bf(u1.w);
                }
            }
#pragma unroll
            for (int m = 0; m < KSM; m++) {
                bf16x8 am = *(bf16x8*)&Dlds[(m * 16 + il) * DPITCH + a0];
#pragma unroll
                for (int nf = 0; nf < 4; nf++)
                    acc[m][nf] = __builtin_amdgcn_mfma_f32_16x16x32_bf16(am, bm[nf], acc[m][nf], 0, 0, 0);
            }
        }

#pragma unroll
        for (int m = 0; m < KSM; m++) {
            float sacc[4] = {0.f, 0.f, 0.f, 0.f};
#pragma unroll
            for (int nf = 0; nf < 4; nf++) {
                int bcol = bbase + nf * 16 + il;
#pragma unroll
                for (int r = 0; r < 4; r++) {
                    int crow = m * 16 + q * 4 + r;
                    float dv = bf2f(Dlds[crow * DPITCH + bcol]);
                    sacc[r] = fmaf(dv, acc[m][nf][r], sacc[r]);
                }
            }
#pragma unroll
            for (int r = 0; r < 4; r++) {
                float v = sacc[r];
                v += __shfl_xor(v, 1);
                v += __shfl_xor(v, 2);
                v += __shfl_xor(v, 4);
                v += __shfl_xor(v, 8);
                if (il == 0) red[w][m * 16 + q * 4 + r] = v;
            }
        }
        __syncthreads();
        if (t < Cc)
            S[k * Cc + t] = red[0][t] + red[1][t] + red[2][t] + red[3][t];
    } else {
        // ---------------- k1 tile: h = s @ W1^T + b1, stats -----------------
        const int bid2 = bid - Cc;
        const int row0 = bid2 * 16;
        const int colw = w * 32;

        f32x4 acc[2];
        acc[0] = (f32x4){0.f,0.f,0.f,0.f};
        acc[1] = (f32x4){0.f,0.f,0.f,0.f};

        const float* arow = s  + (size_t)(row0 + il) * Aa;
        const float* bp0  = W1 + (size_t)(colw + il) * Aa;
        const float* bp1  = W1 + (size_t)(colw + 16 + il) * Aa;

#pragma unroll
        for (int ks = 0; ks < 8; ks++) {
            const int k0 = ks * 32 + q * 8;
            float4 u0 = *(const float4*)&arow[k0];
            float4 u1 = *(const float4*)&arow[k0 + 4];
            bf16x8 am;
            am[0]=f2bf(u0.x); am[1]=f2bf(u0.y); am[2]=f2bf(u0.z); am[3]=f2bf(u0.w);
            am[4]=f2bf(u1.x); am[5]=f2bf(u1.y); am[6]=f2bf(u1.z); am[7]=f2bf(u1.w);
            float4 v0 = *(const float4*)&bp0[k0];
            float4 v1 = *(const float4*)&bp0[k0 + 4];
            bf16x8 bm0;
            bm0[0]=f2bf(v0.x); bm0[1]=f2bf(v0.y); bm0[2]=f2bf(v0.z); bm0[3]=f2bf(v0.w);
            bm0[4]=f2bf(v1.x); bm0[5]=f2bf(v1.y); bm0[6]=f2bf(v1.z); bm0[7]=f2bf(v1.w);
            float4 x0 = *(const float4*)&bp1[k0];
            float4 x1 = *(const float4*)&bp1[k0 + 4];
            bf16x8 bm1;
            bm1[0]=f2bf(x0.x); bm1[1]=f2bf(x0.y); bm1[2]=f2bf(x0.z); bm1[3]=f2bf(x0.w);
            bm1[4]=f2bf(x1.x); bm1[5]=f2bf(x1.y); bm1[6]=f2bf(x1.z); bm1[7]=f2bf(x1.w);
            acc[0] = __builtin_amdgcn_mfma_f32_16x16x32_bf16(am, bm0, acc[0], 0, 0, 0);
            acc[1] = __builtin_amdgcn_mfma_f32_16x16x32_bf16(am, bm1, acc[1], 0, 0, 0);
        }

#pragma unroll
        for (int n = 0; n < 2; n++) {
            const int col = colw + n * 16 + il;
            const float bias = b1[col];
            float s1 = 0.f, s2 = 0.f;
#pragma unroll
            for (int r = 0; r < 4; r++) {
                float v = acc[n][r] + bias;
                hB[(size_t)(row0 + q * 4 + r) * LAT + col] = f2bf(v);
                s1 += v; s2 += v * v;
            }
            s1 += __shfl_xor(s1, 16); s1 += __shfl_xor(s1, 32);
            s2 += __shfl_xor(s2, 16); s2 += __shfl_xor(s2, 32);
            if (q == 0) {
                sums[bid2 * 256 + col]       = s1;
                sums[bid2 * 256 + 128 + col] = s2;
            }
        }
    }
}

// ---------------- K3: f = relu(relu(bn(h)) @ W2^T + b2), bf16 out -------------
// grid 128: block owns 16 rows x N=256; wave w cols [w*64, w*64+64). W2 f32
// converted on the fly (validated in round 5).
__global__ __launch_bounds__(256) void k3_mfma(
    const short* __restrict__ hB, const float* __restrict__ sums,
    const float* __restrict__ gamma, const float* __restrict__ beta,
    const float* __restrict__ W2, const float* __restrict__ b2,
    short* __restrict__ fB)
{
    __shared__ float scL[LAT], shL[LAT];
    const int t = threadIdx.x;
    if (t < 128) {
        float a1 = 0.f, a2 = 0.f;
#pragma unroll 8
        for (int b = 0; b < 128; b++) {
            a1 += sums[b * 256 + t];
            a2 += sums[b * 256 + 128 + t];
        }
        float mu  = a1 * (1.0f / Nn);
        float var = a2 * (1.0f / Nn) - mu * mu;
        float inv = rsqrtf(var + BN_EPS);
        float sc  = gamma[t] * inv;
        scL[t] = sc;
        shL[t] = beta[t] - mu * sc;
    }
    __syncthreads();

    const int w = t >> 6, l = t & 63, il = l & 15, q = l >> 4;
    const int row0 = blockIdx.x * 16;
    const int colw = w * 64;

    f32x4 acc[4];
#pragma unroll
    for (int n = 0; n < 4; n++) acc[n] = (f32x4){0.f,0.f,0.f,0.f};

    const short* arow = hB + (size_t)(row0 + il) * LAT;

#pragma unroll
    for (int ks = 0; ks < 4; ks++) {
        const int k0 = ks * 32 + q * 8;
        bf16x8 ha = *(const bf16x8*)&arow[k0];
        bf16x8 am;
#pragma unroll
        for (int j = 0; j < 8; j++) {
            float fv = fmaf(bf2f(ha[j]), scL[k0 + j], shL[k0 + j]);
            am[j] = f2bf(fmaxf(fv, 0.f));
        }
#pragma unroll
        for (int n = 0; n < 4; n++) {
            const int col = colw + n * 16 + il;
            float4 v0 = *(const float4*)&W2[(size_t)col * LAT + k0];
            float4 v1 = *(const float4*)&W2[(size_t)col * LAT + k0 + 4];
            bf16x8 bm;
            bm[0]=f2bf(v0.x); bm[1]=f2bf(v0.y); bm[2]=f2bf(v0.z); bm[3]=f2bf(v0.w);
            bm[4]=f2bf(v1.x); bm[5]=f2bf(v1.y); bm[6]=f2bf(v1.z); bm[7]=f2bf(v1.w);
            acc[n] = __builtin_amdgcn_mfma_f32_16x16x32_bf16(am, bm, acc[n], 0, 0, 0);
        }
    }

#pragma unroll
    for (int n = 0; n < 4; n++) {
        const int col = colw + n * 16 + il;
        const float bias = b2[col];
#pragma unroll
        for (int r = 0; r < 4; r++) {
            float v = fmaxf(acc[n][r] + bias, 0.f);
            fB[(size_t)(row0 + q * 4 + r) * Aa + col] = f2bf(v);
        }
    }
}

// ---------------- K4: out = f @ Wfc^T + bfc + coef * S[y[n]][c] ---------------
// grid 128: block owns 16 rows x padded N=128; wave w cols [w*32, w*32+32).
// Wfc f32 converted on the fly; rows >= Cc clamped, stores masked (round 5).
__global__ __launch_bounds__(256) void k4_mfma(
    const short* __restrict__ fB, const float* __restrict__ Wfc,
    const float* __restrict__ bfc, const float* __restrict__ S,
    const int* __restrict__ y, const float* __restrict__ ratio,
    float* __restrict__ out)
{
    const int t = threadIdx.x;
    const int w = t >> 6, l = t & 63, il = l & 15, q = l >> 4;
    const int row0 = blockIdx.x * 16;
    const int colw = w * 32;

    f32x4 acc[2];
    acc[0] = (f32x4){0.f,0.f,0.f,0.f};
    acc[1] = (f32x4){0.f,0.f,0.f,0.f};

    const short* arow = fB + (size_t)(row0 + il) * Aa;
    const int crow0 = (colw + il)      < Cc ? (colw + il)      : Cc - 1;
    const int crow1 = (colw + 16 + il) < Cc ? (colw + 16 + il) : Cc - 1;
    const float* bp0 = Wfc + (size_t)crow0 * Aa;
    const float* bp1 = Wfc + (size_t)crow1 * Aa;

#pragma unroll
    for (int ks = 0; ks < 8; ks++) {
        const int k0 = ks * 32 + q * 8;
        bf16x8 am = *(const bf16x8*)&arow[k0];
        float4 v0 = *(const float4*)&bp0[k0];
        float4 v1 = *(const float4*)&bp0[k0 + 4];
        bf16x8 bm0;
        bm0[0]=f2bf(v0.x); bm0[1]=f2bf(v0.y); bm0[2]=f2bf(v0.z); bm0[3]=f2bf(v0.w);
        bm0[4]=f2bf(v1.x); bm0[5]=f2bf(v1.y); bm0[6]=f2bf(v1.z); bm0[7]=f2bf(v1.w);
        float4 x0 = *(const float4*)&bp1[k0];
        float4 x1 = *(const float4*)&bp1[k0 + 4];
        bf16x8 bm1;
        bm1[0]=f2bf(x0.x); bm1[1]=f2bf(x0.y); bm1[2]=f2bf(x0.z); bm1[3]=f2bf(x0.w);
        bm1[4]=f2bf(x1.x); bm1[5]=f2bf(x1.y); bm1[6]=f2bf(x1.z); bm1[7]=f2bf(x1.w);
        acc[0] = __builtin_amdgcn_mfma_f32_16x16x32_bf16(am, bm0, acc[0], 0, 0, 0);
        acc[1] = __builtin_amdgcn_mfma_f32_16x16x32_bf16(am, bm1, acc[1], 0, 0, 0);
    }

    const float coef = 0.5f * ratio[0];
    const int4 yv4 = *(const int4*)&y[row0 + q * 4];
    const int yr[4] = {yv4.x, yv4.y, yv4.z, yv4.w};

#pragma unroll
    for (int n = 0; n < 2; n++) {
        const int col = colw + n * 16 + il;
        if (col < Cc) {
            const float bias = bfc[col];
#pragma unroll
            for (int r = 0; r < 4; r++) {
                out[(size_t)(row0 + q * 4 + r) * Cc + col] =
                    acc[n][r] + bias + coef * S[yr[r] * Cc + col];
            }
        }
    }
}

extern "C" void kernel_launch(void* const* d_in, const int* in_sizes, int n_in,
                              void* d_out, int out_size, void* d_ws, size_t ws_size,
                              hipStream_t stream)
{
    const float* s     = (const float*)d_in[0];
    const int*   y     = (const int*)  d_in[1];
    const float* ratio = (const float*)d_in[2];
    const float* W1    = (const float*)d_in[3];
    const float* b1    = (const float*)d_in[4];
    const float* gamma = (const float*)d_in[5];
    const float* beta  = (const float*)d_in[6];
    const float* W2    = (const float*)d_in[7];
    const float* b2    = (const float*)d_in[8];
    const float* Wfc   = (const float*)d_in[9];
    const float* bfc   = (const float*)d_in[10];
    const float* cov   = (const float*)d_in[11];
    float* out = (float*)d_out;
    float* ws  = (float*)d_ws;

    short* hB   = (short*)(ws + OFF_HB);
    short* fB   = (short*)(ws + OFF_FB);
    float* sums = ws + OFF_SUMS;
    float* S    = ws + OFF_S;

    hipLaunchKernelGGL(kA,      dim3(228), dim3(256), 0, stream,
                       s, W1, b1, Wfc, cov, hB, sums, S);
    hipLaunchKernelGGL(k3_mfma, dim3(128), dim3(256), 0, stream,
                       hB, sums, gamma, beta, W2, b2, fB);
    hipLaunchKernelGGL(k4_mfma, dim3(128), dim3(256), 0, stream,
                       fB, Wfc, bfc, S, y, ratio, out);
}

// Round 7
// 38.795 us; speedup vs baseline: 1.5701x; 1.0184x over previous
//
#include <hip/hip_runtime.h>

#define Nn  2048
#define Aa  256
#define Cc  100
#define LAT 128
#define BN_EPS 1e-5f

// ws layout in floats (everything fully overwritten each call -> no zeroing)
#define OFF_HB   0                         // h bf16 [2048][128] = 131072 floats
#define OFF_SUMS (OFF_HB + Nn*LAT/2)       // 128 blocks * 256 f32
#define OFF_SP   (OFF_SUMS + 128*256)      // Spart [2][100][100] f32

typedef __attribute__((ext_vector_type(8))) short bf16x8;
typedef __attribute__((ext_vector_type(4))) float f32x4;

__device__ __forceinline__ short f2bf(float f) {
    unsigned u = __float_as_uint(f);
    u = (u + 0x7FFFu + ((u >> 16) & 1u)) >> 16;
    return (short)u;
}
__device__ __forceinline__ float bf2f(short h) {
    return __uint_as_float(((unsigned)(unsigned short)h) << 16);
}

// ---------------- A: fused { ks halves (bid<200) | k1 tiles (bid>=200) } ------
// No cross-block communication: ks halves write Spart[2]; k1 writes hB + stats.
#define DPITCH 264     // bf16 pitch: 528 B, odd multiple of 16B

__global__ __launch_bounds__(256) void kA(
    const float* __restrict__ s, const float* __restrict__ W1,
    const float* __restrict__ b1, const float* __restrict__ Wfc,
    const float* __restrict__ cov,
    short* __restrict__ hB, float* __restrict__ sums, float* __restrict__ Spart)
{
    __shared__ __align__(16) char smem[112 * DPITCH * 2 + 4 * 112 * 4];
    const int bid = blockIdx.x;
    const int t = threadIdx.x;
    const int w = t >> 6, l = t & 63, il = l & 15, q = l >> 4;

    if (bid < 200) {
        // ------------- ks half: Spart[nh][k][c], b-range nh*128..+128 -------------
        short* Dlds = (short*)smem;                              // 112 x DPITCH
        float (*red)[112] = (float(*)[112])(smem + 112 * DPITCH * 2);
        const int k  = bid >> 1;
        const int nh = bid & 1;
        const float* covk = cov + (size_t)k * (Aa * Aa);

        {   // stage D = Wfc - Wfc[k] (bf16), rows >= Cc zero; coalesced
            const int c4 = t & 63;
            float4 wk = *(const float4*)&Wfc[(size_t)k * Aa + c4 * 4];
#pragma unroll
            for (int j = 0; j < 28; j++) {
                int row = (t >> 6) + j * 4;
                short4 o;
                if (row < Cc) {
                    float4 v = *(const float4*)&Wfc[(size_t)row * Aa + c4 * 4];
                    o.x = f2bf(v.x - wk.x); o.y = f2bf(v.y - wk.y);
                    o.z = f2bf(v.z - wk.z); o.w = f2bf(v.w - wk.w);
                } else {
                    o.x = 0; o.y = 0; o.z = 0; o.w = 0;
                }
                *(short4*)&Dlds[row * DPITCH + c4 * 4] = o;
            }
        }
        __syncthreads();

        const int bbase = nh * 128 + w * 32;

        f32x4 acc[7][2];
#pragma unroll
        for (int m = 0; m < 7; m++) {
            acc[m][0] = (f32x4){0.f,0.f,0.f,0.f};
            acc[m][1] = (f32x4){0.f,0.f,0.f,0.f};
        }

        const float* brow0 = covk + (size_t)(bbase + il) * Aa;
        const float* brow1 = covk + (size_t)(bbase + 16 + il) * Aa;

#pragma unroll
        for (int sgk = 0; sgk < 8; sgk++) {
            const int a0 = sgk * 32 + q * 8;
            bf16x8 bm0, bm1;
            {
                float4 u0 = *(const float4*)&brow0[a0];
                float4 u1 = *(const float4*)&brow0[a0 + 4];
                bm0[0]=f2bf(u0.x); bm0[1]=f2bf(u0.y); bm0[2]=f2bf(u0.z); bm0[3]=f2bf(u0.w);
                bm0[4]=f2bf(u1.x); bm0[5]=f2bf(u1.y); bm0[6]=f2bf(u1.z); bm0[7]=f2bf(u1.w);
                float4 v0 = *(const float4*)&brow1[a0];
                float4 v1 = *(const float4*)&brow1[a0 + 4];
                bm1[0]=f2bf(v0.x); bm1[1]=f2bf(v0.y); bm1[2]=f2bf(v0.z); bm1[3]=f2bf(v0.w);
                bm1[4]=f2bf(v1.x); bm1[5]=f2bf(v1.y); bm1[6]=f2bf(v1.z); bm1[7]=f2bf(v1.w);
            }
#pragma unroll
            for (int m = 0; m < 7; m++) {
                bf16x8 am = *(bf16x8*)&Dlds[(m * 16 + il) * DPITCH + a0];
                acc[m][0] = __builtin_amdgcn_mfma_f32_16x16x32_bf16(am, bm0, acc[m][0], 0, 0, 0);
                acc[m][1] = __builtin_amdgcn_mfma_f32_16x16x32_bf16(am, bm1, acc[m][1], 0, 0, 0);
            }
        }

#pragma unroll
        for (int m = 0; m < 7; m++) {
            float sacc[4] = {0.f, 0.f, 0.f, 0.f};
#pragma unroll
            for (int nf = 0; nf < 2; nf++) {
                int bcol = bbase + nf * 16 + il;
#pragma unroll
                for (int r = 0; r < 4; r++) {
                    int crow = m * 16 + q * 4 + r;
                    float dv = bf2f(Dlds[crow * DPITCH + bcol]);
                    sacc[r] = fmaf(dv, acc[m][nf][r], sacc[r]);
                }
            }
#pragma unroll
            for (int r = 0; r < 4; r++) {
                float v = sacc[r];
                v += __shfl_xor(v, 1);
                v += __shfl_xor(v, 2);
                v += __shfl_xor(v, 4);
                v += __shfl_xor(v, 8);
                if (il == 0) red[w][m * 16 + q * 4 + r] = v;
            }
        }
        __syncthreads();
        if (t < Cc)
            Spart[nh * (Cc * Cc) + k * Cc + t] =
                red[0][t] + red[1][t] + red[2][t] + red[3][t];
    } else {
        // ---------------- k1 tile: h = s @ W1^T + b1, stats -----------------
        const int bid2 = bid - 200;
        const int row0 = bid2 * 16;
        const int colw = w * 32;

        f32x4 acc[2];
        acc[0] = (f32x4){0.f,0.f,0.f,0.f};
        acc[1] = (f32x4){0.f,0.f,0.f,0.f};

        const float* arow = s  + (size_t)(row0 + il) * Aa;
        const float* bp0  = W1 + (size_t)(colw + il) * Aa;
        const float* bp1  = W1 + (size_t)(colw + 16 + il) * Aa;

#pragma unroll
        for (int ks = 0; ks < 8; ks++) {
            const int k0 = ks * 32 + q * 8;
            float4 u0 = *(const float4*)&arow[k0];
            float4 u1 = *(const float4*)&arow[k0 + 4];
            bf16x8 am;
            am[0]=f2bf(u0.x); am[1]=f2bf(u0.y); am[2]=f2bf(u0.z); am[3]=f2bf(u0.w);
            am[4]=f2bf(u1.x); am[5]=f2bf(u1.y); am[6]=f2bf(u1.z); am[7]=f2bf(u1.w);
            float4 v0 = *(const float4*)&bp0[k0];
            float4 v1 = *(const float4*)&bp0[k0 + 4];
            bf16x8 bm0;
            bm0[0]=f2bf(v0.x); bm0[1]=f2bf(v0.y); bm0[2]=f2bf(v0.z); bm0[3]=f2bf(v0.w);
            bm0[4]=f2bf(v1.x); bm0[5]=f2bf(v1.y); bm0[6]=f2bf(v1.z); bm0[7]=f2bf(v1.w);
            float4 x0 = *(const float4*)&bp1[k0];
            float4 x1 = *(const float4*)&bp1[k0 + 4];
            bf16x8 bm1;
            bm1[0]=f2bf(x0.x); bm1[1]=f2bf(x0.y); bm1[2]=f2bf(x0.z); bm1[3]=f2bf(x0.w);
            bm1[4]=f2bf(x1.x); bm1[5]=f2bf(x1.y); bm1[6]=f2bf(x1.z); bm1[7]=f2bf(x1.w);
            acc[0] = __builtin_amdgcn_mfma_f32_16x16x32_bf16(am, bm0, acc[0], 0, 0, 0);
            acc[1] = __builtin_amdgcn_mfma_f32_16x16x32_bf16(am, bm1, acc[1], 0, 0, 0);
        }

#pragma unroll
        for (int n = 0; n < 2; n++) {
            const int col = colw + n * 16 + il;
            const float bias = b1[col];
            float s1 = 0.f, s2 = 0.f;
#pragma unroll
            for (int r = 0; r < 4; r++) {
                float v = acc[n][r] + bias;
                hB[(size_t)(row0 + q * 4 + r) * LAT + col] = f2bf(v);
                s1 += v; s2 += v * v;
            }
            s1 += __shfl_xor(s1, 16); s1 += __shfl_xor(s1, 32);
            s2 += __shfl_xor(s2, 16); s2 += __shfl_xor(s2, 32);
            if (q == 0) {
                sums[bid2 * 256 + col]       = s1;
                sums[bid2 * 256 + 128 + col] = s2;
            }
        }
    }
}

// ---------------- B: fused k3+k4 per 16-row tile ------------------------------
// BN prologue -> GEMM1 (f tile in LDS, bf16) -> GEMM2 -> +bfc + coef*S gather.
// S ordering guaranteed by kernel boundary (kA wrote Spart).
#define FPITCH 264

__global__ __launch_bounds__(256) void kB(
    const short* __restrict__ hB, const float* __restrict__ sums,
    const float* __restrict__ gamma, const float* __restrict__ beta,
    const float* __restrict__ W2, const float* __restrict__ b2,
    const float* __restrict__ Wfc, const float* __restrict__ bfc,
    const float* __restrict__ Spart, const int* __restrict__ y,
    const float* __restrict__ ratio, float* __restrict__ out)
{
    __shared__ float scL[LAT], shL[LAT];
    __shared__ short fLDS[16 * FPITCH];
    const int t = threadIdx.x;
    const int w = t >> 6, l = t & 63, il = l & 15, q = l >> 4;
    const int row0 = blockIdx.x * 16;

    if (t < 128) {
        float a1 = 0.f, a2 = 0.f;
#pragma unroll 8
        for (int b = 0; b < 128; b++) {
            a1 += sums[b * 256 + t];
            a2 += sums[b * 256 + 128 + t];
        }
        float mu  = a1 * (1.0f / Nn);
        float var = a2 * (1.0f / Nn) - mu * mu;
        float inv = rsqrtf(var + BN_EPS);
        float sc  = gamma[t] * inv;
        scL[t] = sc;
        shL[t] = beta[t] - mu * sc;
    }
    __syncthreads();

    // ---- GEMM1: f_tile = relu(bn(h_tile) @ W2^T + b2), cols w*64..+64 ----
    f32x4 acc3[4];
#pragma unroll
    for (int n = 0; n < 4; n++) acc3[n] = (f32x4){0.f,0.f,0.f,0.f};

    const short* arow = hB + (size_t)(row0 + il) * LAT;
#pragma unroll
    for (int ks = 0; ks < 4; ks++) {
        const int k0 = ks * 32 + q * 8;
        bf16x8 ha = *(const bf16x8*)&arow[k0];
        bf16x8 am;
#pragma unroll
        for (int j = 0; j < 8; j++) {
            float fv = fmaf(bf2f(ha[j]), scL[k0 + j], shL[k0 + j]);
            am[j] = f2bf(fmaxf(fv, 0.f));
        }
#pragma unroll
        for (int n = 0; n < 4; n++) {
            const int col = w * 64 + n * 16 + il;
            float4 v0 = *(const float4*)&W2[(size_t)col * LAT + k0];
            float4 v1 = *(const float4*)&W2[(size_t)col * LAT + k0 + 4];
            bf16x8 bm;
            bm[0]=f2bf(v0.x); bm[1]=f2bf(v0.y); bm[2]=f2bf(v0.z); bm[3]=f2bf(v0.w);
            bm[4]=f2bf(v1.x); bm[5]=f2bf(v1.y); bm[6]=f2bf(v1.z); bm[7]=f2bf(v1.w);
            acc3[n] = __builtin_amdgcn_mfma_f32_16x16x32_bf16(am, bm, acc3[n], 0, 0, 0);
        }
    }
#pragma unroll
    for (int n = 0; n < 4; n++) {
        const int col = w * 64 + n * 16 + il;
        const float bias = b2[col];
#pragma unroll
        for (int r = 0; r < 4; r++) {
            float v = fmaxf(acc3[n][r] + bias, 0.f);
            fLDS[(q * 4 + r) * FPITCH + col] = f2bf(v);
        }
    }
    __syncthreads();

    // ---- GEMM2: out_tile = f_tile @ Wfc^T, cols w*32..+32 ----
    f32x4 acc4[2];
    acc4[0] = (f32x4){0.f,0.f,0.f,0.f};
    acc4[1] = (f32x4){0.f,0.f,0.f,0.f};
#pragma unroll
    for (int ks = 0; ks < 8; ks++) {
        const int k0 = ks * 32 + q * 8;
        bf16x8 am = *(const bf16x8*)&fLDS[il * FPITCH + k0];
#pragma unroll
        for (int n = 0; n < 2; n++) {
            const int col = w * 32 + n * 16 + il;
            const int crow = col < Cc ? col : Cc - 1;   // clamp; masked at store
            float4 v0 = *(const float4*)&Wfc[(size_t)crow * Aa + k0];
            float4 v1 = *(const float4*)&Wfc[(size_t)crow * Aa + k0 + 4];
            bf16x8 bm;
            bm[0]=f2bf(v0.x); bm[1]=f2bf(v0.y); bm[2]=f2bf(v0.z); bm[3]=f2bf(v0.w);
            bm[4]=f2bf(v1.x); bm[5]=f2bf(v1.y); bm[6]=f2bf(v1.z); bm[7]=f2bf(v1.w);
            acc4[n] = __builtin_amdgcn_mfma_f32_16x16x32_bf16(am, bm, acc4[n], 0, 0, 0);
        }
    }

    const float coef = 0.5f * ratio[0];
    const int4 yv4 = *(const int4*)&y[row0 + q * 4];
    const int yr[4] = {yv4.x, yv4.y, yv4.z, yv4.w};

#pragma unroll
    for (int n = 0; n < 2; n++) {
        const int col = w * 32 + n * 16 + il;
        if (col < Cc) {
            const float bias = bfc[col];
#pragma unroll
            for (int r = 0; r < 4; r++) {
                float sp0 = Spart[yr[r] * Cc + col];
                float sp1 = Spart[Cc * Cc + yr[r] * Cc + col];
                out[(size_t)(row0 + q * 4 + r) * Cc + col] =
                    acc4[n][r] + bias + coef * (sp0 + sp1);
            }
        }
    }
}

extern "C" void kernel_launch(void* const* d_in, const int* in_sizes, int n_in,
                              void* d_out, int out_size, void* d_ws, size_t ws_size,
                              hipStream_t stream)
{
    const float* s     = (const float*)d_in[0];
    const int*   y     = (const int*)  d_in[1];
    const float* ratio = (const float*)d_in[2];
    const float* W1    = (const float*)d_in[3];
    const float* b1    = (const float*)d_in[4];
    const float* gamma = (const float*)d_in[5];
    const float* beta  = (const float*)d_in[6];
    const float* W2    = (const float*)d_in[7];
    const float* b2    = (const float*)d_in[8];
    const float* Wfc   = (const float*)d_in[9];
    const float* bfc   = (const float*)d_in[10];
    const float* cov   = (const float*)d_in[11];
    float* out = (float*)d_out;
    float* ws  = (float*)d_ws;

    short* hB    = (short*)(ws + OFF_HB);
    float* sums  = ws + OFF_SUMS;
    float* Spart = ws + OFF_SP;

    hipLaunchKernelGGL(kA, dim3(328), dim3(256), 0, stream,
                       s, W1, b1, Wfc, cov, hB, sums, Spart);
    hipLaunchKernelGGL(kB, dim3(128), dim3(256), 0, stream,
                       hB, sums, gamma, beta, W2, b2, Wfc, bfc, Spart, y, ratio, out);
}

// Round 8
// 35.236 us; speedup vs baseline: 1.7286x; 1.1010x over previous
//
#include <hip/hip_runtime.h>
#include <hip/hip_bf16.h>

#define Nn  2048
#define Aa  256
#define Cc  100
#define LAT 128
#define BN_EPS 1e-5f

// ws layout in floats (everything fully overwritten each call -> no zeroing)
#define OFF_HB   0                         // h bf16 [2048][128] = 131072 floats
#define OFF_SUMS (OFF_HB + Nn*LAT/2)       // 128 blocks * 256 f32
#define OFF_SP   (OFF_SUMS + 128*256)      // Spart [4][100][100] f32
#define OFF_W2B  (OFF_SP + 4*Cc*Cc)        // W2 bf16 [256][128] = 16384 floats
#define OFF_WFB  (OFF_W2B + Aa*LAT/2)      // Wfc bf16 padded [128][256] = 16384 floats

typedef __attribute__((ext_vector_type(8))) short bf16x8;
typedef __attribute__((ext_vector_type(4))) float f32x4;

// native RNE conversion -> compiler emits v_cvt_pk_bf16_f32 pairs
__device__ __forceinline__ short f2bf(float f) {
    return (short)__bfloat16_as_ushort(__float2bfloat16(f));
}
__device__ __forceinline__ float bf2f(short h) {
    return __uint_as_float(((unsigned)(unsigned short)h) << 16);
}

// ---------------- A: fused { ks quarters | k1 tiles | weight conversions } ----
// bid 0..399   : ks quarter (k = bid>>2, b-range = (bid&3)*64..+64) -> Spart
// bid 400..527 : k1 16-row tile -> hB + per-block stats
// bid 528      : W2 -> bf16    bid 529 : Wfc -> bf16 padded [128][256]
#define DPITCH 264     // bf16 pitch: 528 B, odd multiple of 16B

__global__ __launch_bounds__(256) void kA(
    const float* __restrict__ s, const float* __restrict__ W1,
    const float* __restrict__ b1, const float* __restrict__ Wfc,
    const float* __restrict__ W2, const float* __restrict__ cov,
    short* __restrict__ hB, float* __restrict__ sums, float* __restrict__ Spart,
    short* __restrict__ W2b, short* __restrict__ Wfcb)
{
    __shared__ __align__(16) char smem[112 * DPITCH * 2 + 4 * 112 * 4];
    const int bid = blockIdx.x;
    const int t = threadIdx.x;
    const int w = t >> 6, l = t & 63, il = l & 15, q = l >> 4;

    if (bid < 400) {
        // ---- ks quarter: Spart[nq][k][c] over b in [nq*64, nq*64+64) ----
        short* Dlds = (short*)smem;                              // 112 x DPITCH
        float (*red)[112] = (float(*)[112])(smem + 112 * DPITCH * 2);
        const int k  = bid >> 2;
        const int nq = bid & 3;
        const float* covk = cov + (size_t)k * (Aa * Aa);

        {   // stage D = Wfc - Wfc[k] (bf16), rows >= Cc zero; coalesced
            const int c4 = t & 63;
            float4 wk = *(const float4*)&Wfc[(size_t)k * Aa + c4 * 4];
#pragma unroll
            for (int j = 0; j < 28; j++) {
                int row = (t >> 6) + j * 4;
                short4 o;
                if (row < Cc) {
                    float4 v = *(const float4*)&Wfc[(size_t)row * Aa + c4 * 4];
                    o.x = f2bf(v.x - wk.x); o.y = f2bf(v.y - wk.y);
                    o.z = f2bf(v.z - wk.z); o.w = f2bf(v.w - wk.w);
                } else {
                    o.x = 0; o.y = 0; o.z = 0; o.w = 0;
                }
                *(short4*)&Dlds[row * DPITCH + c4 * 4] = o;
            }
        }
        __syncthreads();

        const int bbase = nq * 64 + w * 16;

        f32x4 acc[7];
#pragma unroll
        for (int m = 0; m < 7; m++) acc[m] = (f32x4){0.f,0.f,0.f,0.f};

        const float* brow = covk + (size_t)(bbase + il) * Aa;

#pragma unroll
        for (int sgk = 0; sgk < 8; sgk++) {
            const int a0 = sgk * 32 + q * 8;
            float4 u0 = *(const float4*)&brow[a0];
            float4 u1 = *(const float4*)&brow[a0 + 4];
            bf16x8 bm;
            bm[0]=f2bf(u0.x); bm[1]=f2bf(u0.y); bm[2]=f2bf(u0.z); bm[3]=f2bf(u0.w);
            bm[4]=f2bf(u1.x); bm[5]=f2bf(u1.y); bm[6]=f2bf(u1.z); bm[7]=f2bf(u1.w);
#pragma unroll
            for (int m = 0; m < 7; m++) {
                bf16x8 am = *(bf16x8*)&Dlds[(m * 16 + il) * DPITCH + a0];
                acc[m] = __builtin_amdgcn_mfma_f32_16x16x32_bf16(am, bm, acc[m], 0, 0, 0);
            }
        }

#pragma unroll
        for (int m = 0; m < 7; m++) {
            const int bcol = bbase + il;
            float sacc[4];
#pragma unroll
            for (int r = 0; r < 4; r++) {
                int crow = m * 16 + q * 4 + r;
                sacc[r] = bf2f(Dlds[crow * DPITCH + bcol]) * acc[m][r];
            }
#pragma unroll
            for (int r = 0; r < 4; r++) {
                float v = sacc[r];
                v += __shfl_xor(v, 1);
                v += __shfl_xor(v, 2);
                v += __shfl_xor(v, 4);
                v += __shfl_xor(v, 8);
                if (il == 0) red[w][m * 16 + q * 4 + r] = v;
            }
        }
        __syncthreads();
        if (t < Cc)
            Spart[nq * (Cc * Cc) + k * Cc + t] =
                red[0][t] + red[1][t] + red[2][t] + red[3][t];
    } else if (bid < 528) {
        // ---------------- k1 tile: h = s @ W1^T + b1, stats -----------------
        const int bid2 = bid - 400;
        const int row0 = bid2 * 16;
        const int colw = w * 32;

        f32x4 acc[2];
        acc[0] = (f32x4){0.f,0.f,0.f,0.f};
        acc[1] = (f32x4){0.f,0.f,0.f,0.f};

        const float* arow = s  + (size_t)(row0 + il) * Aa;
        const float* bp0  = W1 + (size_t)(colw + il) * Aa;
        const float* bp1  = W1 + (size_t)(colw + 16 + il) * Aa;

#pragma unroll
        for (int ks = 0; ks < 8; ks++) {
            const int k0 = ks * 32 + q * 8;
            float4 u0 = *(const float4*)&arow[k0];
            float4 u1 = *(const float4*)&arow[k0 + 4];
            bf16x8 am;
            am[0]=f2bf(u0.x); am[1]=f2bf(u0.y); am[2]=f2bf(u0.z); am[3]=f2bf(u0.w);
            am[4]=f2bf(u1.x); am[5]=f2bf(u1.y); am[6]=f2bf(u1.z); am[7]=f2bf(u1.w);
            float4 v0 = *(const float4*)&bp0[k0];
            float4 v1 = *(const float4*)&bp0[k0 + 4];
            bf16x8 bm0;
            bm0[0]=f2bf(v0.x); bm0[1]=f2bf(v0.y); bm0[2]=f2bf(v0.z); bm0[3]=f2bf(v0.w);
            bm0[4]=f2bf(v1.x); bm0[5]=f2bf(v1.y); bm0[6]=f2bf(v1.z); bm0[7]=f2bf(v1.w);
            float4 x0 = *(const float4*)&bp1[k0];
            float4 x1 = *(const float4*)&bp1[k0 + 4];
            bf16x8 bm1;
            bm1[0]=f2bf(x0.x); bm1[1]=f2bf(x0.y); bm1[2]=f2bf(x0.z); bm1[3]=f2bf(x0.w);
            bm1[4]=f2bf(x1.x); bm1[5]=f2bf(x1.y); bm1[6]=f2bf(x1.z); bm1[7]=f2bf(x1.w);
            acc[0] = __builtin_amdgcn_mfma_f32_16x16x32_bf16(am, bm0, acc[0], 0, 0, 0);
            acc[1] = __builtin_amdgcn_mfma_f32_16x16x32_bf16(am, bm1, acc[1], 0, 0, 0);
        }

#pragma unroll
        for (int n = 0; n < 2; n++) {
            const int col = colw + n * 16 + il;
            const float bias = b1[col];
            float s1 = 0.f, s2 = 0.f;
#pragma unroll
            for (int r = 0; r < 4; r++) {
                float v = acc[n][r] + bias;
                hB[(size_t)(row0 + q * 4 + r) * LAT + col] = f2bf(v);
                s1 += v; s2 += v * v;
            }
            s1 += __shfl_xor(s1, 16); s1 += __shfl_xor(s1, 32);
            s2 += __shfl_xor(s2, 16); s2 += __shfl_xor(s2, 32);
            if (q == 0) {
                sums[bid2 * 256 + col]       = s1;
                sums[bid2 * 256 + 128 + col] = s2;
            }
        }
    } else if (bid == 528) {
        // ---------------- W2 -> bf16 ----------------
        for (int i = t * 4; i < Aa * LAT; i += 1024) {
            float4 v = *(const float4*)&W2[i];
            short4 o = {f2bf(v.x), f2bf(v.y), f2bf(v.z), f2bf(v.w)};
            *(short4*)&W2b[i] = o;
        }
    } else {
        // ---------------- Wfc -> bf16, padded [128][256] ----------------
        for (int i = t * 4; i < 128 * Aa; i += 1024) {
            int row = i >> 8;
            short4 o = {0, 0, 0, 0};
            if (row < Cc) {
                float4 v = *(const float4*)&Wfc[i];
                o.x = f2bf(v.x); o.y = f2bf(v.y); o.z = f2bf(v.z); o.w = f2bf(v.w);
            }
            *(short4*)&Wfcb[i] = o;
        }
    }
}

// ---------------- B: fused k3+k4 per 16-row tile ------------------------------
// BN prologue -> GEMM1 (f tile in LDS, bf16) -> GEMM2 -> +bfc + coef*S gather.
// W2b/Wfcb pre-converted bf16 (kA); ordering via kernel boundary.
#define FPITCH 264

__global__ __launch_bounds__(256) void kB(
    const short* __restrict__ hB, const float* __restrict__ sums,
    const float* __restrict__ gamma, const float* __restrict__ beta,
    const short* __restrict__ W2b, const float* __restrict__ b2,
    const short* __restrict__ Wfcb, const float* __restrict__ bfc,
    const float* __restrict__ Spart, const int* __restrict__ y,
    const float* __restrict__ ratio, float* __restrict__ out)
{
    __shared__ float scL[LAT], shL[LAT];
    __shared__ short fLDS[16 * FPITCH];
    const int t = threadIdx.x;
    const int w = t >> 6, l = t & 63, il = l & 15, q = l >> 4;
    const int row0 = blockIdx.x * 16;

    if (t < 128) {
        float a1 = 0.f, a2 = 0.f;
#pragma unroll 8
        for (int b = 0; b < 128; b++) {
            a1 += sums[b * 256 + t];
            a2 += sums[b * 256 + 128 + t];
        }
        float mu  = a1 * (1.0f / Nn);
        float var = a2 * (1.0f / Nn) - mu * mu;
        float inv = rsqrtf(var + BN_EPS);
        float sc  = gamma[t] * inv;
        scL[t] = sc;
        shL[t] = beta[t] - mu * sc;
    }
    __syncthreads();

    // ---- GEMM1: f_tile = relu(bn(h_tile) @ W2^T + b2), cols w*64..+64 ----
    f32x4 acc3[4];
#pragma unroll
    for (int n = 0; n < 4; n++) acc3[n] = (f32x4){0.f,0.f,0.f,0.f};

    const short* arow = hB + (size_t)(row0 + il) * LAT;
#pragma unroll
    for (int ks = 0; ks < 4; ks++) {
        const int k0 = ks * 32 + q * 8;
        bf16x8 ha = *(const bf16x8*)&arow[k0];
        bf16x8 am;
#pragma unroll
        for (int j = 0; j < 8; j++) {
            float fv = fmaf(bf2f(ha[j]), scL[k0 + j], shL[k0 + j]);
            am[j] = f2bf(fmaxf(fv, 0.f));
        }
#pragma unroll
        for (int n = 0; n < 4; n++) {
            const int col = w * 64 + n * 16 + il;
            bf16x8 bm = *(const bf16x8*)&W2b[(size_t)col * LAT + k0];
            acc3[n] = __builtin_amdgcn_mfma_f32_16x16x32_bf16(am, bm, acc3[n], 0, 0, 0);
        }
    }
#pragma unroll
    for (int n = 0; n < 4; n++) {
        const int col = w * 64 + n * 16 + il;
        const float bias = b2[col];
#pragma unroll
        for (int r = 0; r < 4; r++) {
            float v = fmaxf(acc3[n][r] + bias, 0.f);
            fLDS[(q * 4 + r) * FPITCH + col] = f2bf(v);
        }
    }
    __syncthreads();

    // ---- GEMM2: out_tile = f_tile @ Wfc^T, cols w*32..+32 ----
    f32x4 acc4[2];
    acc4[0] = (f32x4){0.f,0.f,0.f,0.f};
    acc4[1] = (f32x4){0.f,0.f,0.f,0.f};
#pragma unroll
    for (int ks = 0; ks < 8; ks++) {
        const int k0 = ks * 32 + q * 8;
        bf16x8 am = *(const bf16x8*)&fLDS[il * FPITCH + k0];
#pragma unroll
        for (int n = 0; n < 2; n++) {
            const int col = w * 32 + n * 16 + il;      // padded rows are zero
            bf16x8 bm = *(const bf16x8*)&Wfcb[(size_t)col * Aa + k0];
            acc4[n] = __builtin_amdgcn_mfma_f32_16x16x32_bf16(am, bm, acc4[n], 0, 0, 0);
        }
    }

    const float coef = 0.5f * ratio[0];
    const int4 yv4 = *(const int4*)&y[row0 + q * 4];
    const int yr[4] = {yv4.x, yv4.y, yv4.z, yv4.w};

#pragma unroll
    for (int n = 0; n < 2; n++) {
        const int col = w * 32 + n * 16 + il;
        if (col < Cc) {
            const float bias = bfc[col];
#pragma unroll
            for (int r = 0; r < 4; r++) {
                const float* sp = &Spart[yr[r] * Cc + col];
                float sv = sp[0] + sp[Cc*Cc] + sp[2*Cc*Cc] + sp[3*Cc*Cc];
                out[(size_t)(row0 + q * 4 + r) * Cc + col] =
                    acc4[n][r] + bias + coef * sv;
            }
        }
    }
}

extern "C" void kernel_launch(void* const* d_in, const int* in_sizes, int n_in,
                              void* d_out, int out_size, void* d_ws, size_t ws_size,
                              hipStream_t stream)
{
    const float* s     = (const float*)d_in[0];
    const int*   y     = (const int*)  d_in[1];
    const float* ratio = (const float*)d_in[2];
    const float* W1    = (const float*)d_in[3];
    const float* b1    = (const float*)d_in[4];
    const float* gamma = (const float*)d_in[5];
    const float* beta  = (const float*)d_in[6];
    const float* W2    = (const float*)d_in[7];
    const float* b2    = (const float*)d_in[8];
    const float* Wfc   = (const float*)d_in[9];
    const float* bfc   = (const float*)d_in[10];
    const float* cov   = (const float*)d_in[11];
    float* out = (float*)d_out;
    float* ws  = (float*)d_ws;

    short* hB    = (short*)(ws + OFF_HB);
    float* sums  = ws + OFF_SUMS;
    float* Spart = ws + OFF_SP;
    short* W2b   = (short*)(ws + OFF_W2B);
    short* Wfcb  = (short*)(ws + OFF_WFB);

    hipLaunchKernelGGL(kA, dim3(530), dim3(256), 0, stream,
                       s, W1, b1, Wfc, W2, cov, hB, sums, Spart, W2b, Wfcb);
    hipLaunchKernelGGL(kB, dim3(128), dim3(256), 0, stream,
                       hB, sums, gamma, beta, W2b, b2, Wfcb, bfc, Spart, y, ratio, out);
}

// Round 9
// 34.802 us; speedup vs baseline: 1.7502x; 1.0125x over previous
//
#include <hip/hip_runtime.h>
#include <hip/hip_bf16.h>

#define Nn  2048
#define Aa  256
#define Cc  100
#define LAT 128
#define BN_EPS 1e-5f

// ws layout in floats (everything fully overwritten each call -> no zeroing)
#define OFF_HB   0                         // h bf16 [2048][128] = 131072 floats
#define OFF_SUMS (OFF_HB + Nn*LAT/2)       // 128 blocks * 256 f32
#define OFF_SP   (OFF_SUMS + 128*256)      // Spart [2][100][100] f32
#define OFF_W2B  (OFF_SP + 2*Cc*Cc)        // W2 bf16 [256][128]
#define OFF_WFB  (OFF_W2B + Aa*LAT/2)      // Wfc bf16 padded [128][256]

typedef __attribute__((ext_vector_type(8))) short bf16x8;
typedef __attribute__((ext_vector_type(4))) float f32x4;

// native RNE conversion -> compiler emits v_cvt_pk_bf16_f32 pairs
__device__ __forceinline__ short f2bf(float f) {
    return (short)__bfloat16_as_ushort(__float2bfloat16(f));
}
__device__ __forceinline__ float bf2f(short h) {
    return __uint_as_float(((unsigned)(unsigned short)h) << 16);
}

#define DPITCH 264     // bf16 pitch: 528 B, odd multiple of 16B

// ---- ks body: block (k, ch, bh). Stages MSZ*16 D-rows (c = ch*64 ..), computes
// S contribution over b in [bh*128, bh*128+128), wave w owns 32 b-cols (nf=2).
template<int MSZ>
__device__ __forceinline__ void ks_body(
    const float* __restrict__ Wfc, const float* __restrict__ cov,
    float* __restrict__ Spart, short* Dlds, float (*red)[64],
    int k, int ch, int bh, int t, int w, int il, int q)
{
    const float* covk = cov + (size_t)k * (Aa * Aa);
    const int c0 = ch * 64;

    {   // stage D rows (bf16), rows past Cc zero; coalesced
        const int c4 = t & 63;
        float4 wk = *(const float4*)&Wfc[(size_t)k * Aa + c4 * 4];
#pragma unroll
        for (int j = 0; j < MSZ * 4; j++) {
            int row = (t >> 6) + j * 4;       // local row 0..MSZ*16-1
            int g = c0 + row;
            short4 o = {0, 0, 0, 0};
            if (g < Cc) {
                float4 v = *(const float4*)&Wfc[(size_t)g * Aa + c4 * 4];
                o.x = f2bf(v.x - wk.x); o.y = f2bf(v.y - wk.y);
                o.z = f2bf(v.z - wk.z); o.w = f2bf(v.w - wk.w);
            }
            *(short4*)&Dlds[row * DPITCH + c4 * 4] = o;
        }
    }
    __syncthreads();

    const int bbase = bh * 128 + w * 32;

    f32x4 acc[MSZ][2];
#pragma unroll
    for (int m = 0; m < MSZ; m++) {
        acc[m][0] = (f32x4){0.f,0.f,0.f,0.f};
        acc[m][1] = (f32x4){0.f,0.f,0.f,0.f};
    }

    const float* brow0 = covk + (size_t)(bbase + il) * Aa;
    const float* brow1 = covk + (size_t)(bbase + 16 + il) * Aa;

#pragma unroll
    for (int sgk = 0; sgk < 8; sgk++) {
        const int a0 = sgk * 32 + q * 8;
        bf16x8 bm0, bm1;
        {
            float4 u0 = *(const float4*)&brow0[a0];
            float4 u1 = *(const float4*)&brow0[a0 + 4];
            bm0[0]=f2bf(u0.x); bm0[1]=f2bf(u0.y); bm0[2]=f2bf(u0.z); bm0[3]=f2bf(u0.w);
            bm0[4]=f2bf(u1.x); bm0[5]=f2bf(u1.y); bm0[6]=f2bf(u1.z); bm0[7]=f2bf(u1.w);
            float4 v0 = *(const float4*)&brow1[a0];
            float4 v1 = *(const float4*)&brow1[a0 + 4];
            bm1[0]=f2bf(v0.x); bm1[1]=f2bf(v0.y); bm1[2]=f2bf(v0.z); bm1[3]=f2bf(v0.w);
            bm1[4]=f2bf(v1.x); bm1[5]=f2bf(v1.y); bm1[6]=f2bf(v1.z); bm1[7]=f2bf(v1.w);
        }
#pragma unroll
        for (int m = 0; m < MSZ; m++) {
            bf16x8 am = *(bf16x8*)&Dlds[(m * 16 + il) * DPITCH + a0];
            acc[m][0] = __builtin_amdgcn_mfma_f32_16x16x32_bf16(am, bm0, acc[m][0], 0, 0, 0);
            acc[m][1] = __builtin_amdgcn_mfma_f32_16x16x32_bf16(am, bm1, acc[m][1], 0, 0, 0);
        }
    }

#pragma unroll
    for (int m = 0; m < MSZ; m++) {
        float sacc[4] = {0.f, 0.f, 0.f, 0.f};
#pragma unroll
        for (int nf = 0; nf < 2; nf++) {
            int bcol = bbase + nf * 16 + il;
#pragma unroll
            for (int r = 0; r < 4; r++) {
                int crow = m * 16 + q * 4 + r;
                float dv = bf2f(Dlds[crow * DPITCH + bcol]);
                sacc[r] = fmaf(dv, acc[m][nf][r], sacc[r]);
            }
        }
#pragma unroll
        for (int r = 0; r < 4; r++) {
            float v = sacc[r];
            v += __shfl_xor(v, 1);
            v += __shfl_xor(v, 2);
            v += __shfl_xor(v, 4);
            v += __shfl_xor(v, 8);
            if (il == 0) red[w][m * 16 + q * 4 + r] = v;
        }
    }
    __syncthreads();
    if (t < MSZ * 16) {
        int c = c0 + t;
        if (c < Cc)
            Spart[bh * (Cc * Cc) + k * Cc + c] =
                red[0][t] + red[1][t] + red[2][t] + red[3][t];
    }
}

// ---------------- A: fused { ks (k,ch,bh) | k1 tiles | weight conversions } ---
// bid 0..399   : ks  (k = bid>>2, ch = (bid>>1)&1, bh = bid&1) -> Spart[bh]
// bid 400..527 : k1 16-row tile -> hB + per-block stats
// bid 528      : W2 -> bf16    bid 529 : Wfc -> bf16 padded [128][256]
__global__ __launch_bounds__(256) void kA(
    const float* __restrict__ s, const float* __restrict__ W1,
    const float* __restrict__ b1, const float* __restrict__ Wfc,
    const float* __restrict__ W2, const float* __restrict__ cov,
    short* __restrict__ hB, float* __restrict__ sums, float* __restrict__ Spart,
    short* __restrict__ W2b, short* __restrict__ Wfcb)
{
    __shared__ __align__(16) char smem[64 * DPITCH * 2 + 4 * 64 * 4];  // 34,816 B
    const int bid = blockIdx.x;
    const int t = threadIdx.x;
    const int w = t >> 6, l = t & 63, il = l & 15, q = l >> 4;

    if (bid < 400) {
        short* Dlds = (short*)smem;
        float (*red)[64] = (float(*)[64])(smem + 64 * DPITCH * 2);
        const int k  = bid >> 2;
        const int ch = (bid >> 1) & 1;
        const int bh = bid & 1;
        if (ch == 0)
            ks_body<4>(Wfc, cov, Spart, Dlds, red, k, 0, bh, t, w, il, q);
        else
            ks_body<3>(Wfc, cov, Spart, Dlds, red, k, 1, bh, t, w, il, q);
    } else if (bid < 528) {
        // ---------------- k1 tile: h = s @ W1^T + b1, stats -----------------
        const int bid2 = bid - 400;
        const int row0 = bid2 * 16;
        const int colw = w * 32;

        f32x4 acc[2];
        acc[0] = (f32x4){0.f,0.f,0.f,0.f};
        acc[1] = (f32x4){0.f,0.f,0.f,0.f};

        const float* arow = s  + (size_t)(row0 + il) * Aa;
        const float* bp0  = W1 + (size_t)(colw + il) * Aa;
        const float* bp1  = W1 + (size_t)(colw + 16 + il) * Aa;

#pragma unroll
        for (int ks = 0; ks < 8; ks++) {
            const int k0 = ks * 32 + q * 8;
            float4 u0 = *(const float4*)&arow[k0];
            float4 u1 = *(const float4*)&arow[k0 + 4];
            bf16x8 am;
            am[0]=f2bf(u0.x); am[1]=f2bf(u0.y); am[2]=f2bf(u0.z); am[3]=f2bf(u0.w);
            am[4]=f2bf(u1.x); am[5]=f2bf(u1.y); am[6]=f2bf(u1.z); am[7]=f2bf(u1.w);
            float4 v0 = *(const float4*)&bp0[k0];
            float4 v1 = *(const float4*)&bp0[k0 + 4];
            bf16x8 bm0;
            bm0[0]=f2bf(v0.x); bm0[1]=f2bf(v0.y); bm0[2]=f2bf(v0.z); bm0[3]=f2bf(v0.w);
            bm0[4]=f2bf(v1.x); bm0[5]=f2bf(v1.y); bm0[6]=f2bf(v1.z); bm0[7]=f2bf(v1.w);
            float4 x0 = *(const float4*)&bp1[k0];
            float4 x1 = *(const float4*)&bp1[k0 + 4];
            bf16x8 bm1;
            bm1[0]=f2bf(x0.x); bm1[1]=f2bf(x0.y); bm1[2]=f2bf(x0.z); bm1[3]=f2bf(x0.w);
            bm1[4]=f2bf(x1.x); bm1[5]=f2bf(x1.y); bm1[6]=f2bf(x1.z); bm1[7]=f2bf(x1.w);
            acc[0] = __builtin_amdgcn_mfma_f32_16x16x32_bf16(am, bm0, acc[0], 0, 0, 0);
            acc[1] = __builtin_amdgcn_mfma_f32_16x16x32_bf16(am, bm1, acc[1], 0, 0, 0);
        }

#pragma unroll
        for (int n = 0; n < 2; n++) {
            const int col = colw + n * 16 + il;
            const float bias = b1[col];
            float s1 = 0.f, s2 = 0.f;
#pragma unroll
            for (int r = 0; r < 4; r++) {
                float v = acc[n][r] + bias;
                hB[(size_t)(row0 + q * 4 + r) * LAT + col] = f2bf(v);
                s1 += v; s2 += v * v;
            }
            s1 += __shfl_xor(s1, 16); s1 += __shfl_xor(s1, 32);
            s2 += __shfl_xor(s2, 16); s2 += __shfl_xor(s2, 32);
            if (q == 0) {
                sums[bid2 * 256 + col]       = s1;
                sums[bid2 * 256 + 128 + col] = s2;
            }
        }
    } else if (bid == 528) {
        // ---------------- W2 -> bf16 ----------------
        for (int i = t * 4; i < Aa * LAT; i += 1024) {
            float4 v = *(const float4*)&W2[i];
            short4 o = {f2bf(v.x), f2bf(v.y), f2bf(v.z), f2bf(v.w)};
            *(short4*)&W2b[i] = o;
        }
    } else {
        // ---------------- Wfc -> bf16, padded [128][256] ----------------
        for (int i = t * 4; i < 128 * Aa; i += 1024) {
            int row = i >> 8;
            short4 o = {0, 0, 0, 0};
            if (row < Cc) {
                float4 v = *(const float4*)&Wfc[i];
                o.x = f2bf(v.x); o.y = f2bf(v.y); o.z = f2bf(v.z); o.w = f2bf(v.w);
            }
            *(short4*)&Wfcb[i] = o;
        }
    }
}

// ---------------- B: fused k3+k4 per 16-row tile ------------------------------
// BN prologue -> GEMM1 (f tile in LDS, bf16) -> GEMM2 -> +bfc + coef*S gather.
#define FPITCH 264

__global__ __launch_bounds__(256) void kB(
    const short* __restrict__ hB, const float* __restrict__ sums,
    const float* __restrict__ gamma, const float* __restrict__ beta,
    const short* __restrict__ W2b, const float* __restrict__ b2,
    const short* __restrict__ Wfcb, const float* __restrict__ bfc,
    const float* __restrict__ Spart, const int* __restrict__ y,
    const float* __restrict__ ratio, float* __restrict__ out)
{
    __shared__ float scL[LAT], shL[LAT];
    __shared__ short fLDS[16 * FPITCH];
    const int t = threadIdx.x;
    const int w = t >> 6, l = t & 63, il = l & 15, q = l >> 4;
    const int row0 = blockIdx.x * 16;

    if (t < 128) {
        float a1 = 0.f, a2 = 0.f;
#pragma unroll 8
        for (int b = 0; b < 128; b++) {
            a1 += sums[b * 256 + t];
            a2 += sums[b * 256 + 128 + t];
        }
        float mu  = a1 * (1.0f / Nn);
        float var = a2 * (1.0f / Nn) - mu * mu;
        float inv = rsqrtf(var + BN_EPS);
        float sc  = gamma[t] * inv;
        scL[t] = sc;
        shL[t] = beta[t] - mu * sc;
    }
    __syncthreads();

    // ---- GEMM1: f_tile = relu(bn(h_tile) @ W2^T + b2), cols w*64..+64 ----
    f32x4 acc3[4];
#pragma unroll
    for (int n = 0; n < 4; n++) acc3[n] = (f32x4){0.f,0.f,0.f,0.f};

    const short* arow = hB + (size_t)(row0 + il) * LAT;
#pragma unroll
    for (int ks = 0; ks < 4; ks++) {
        const int k0 = ks * 32 + q * 8;
        bf16x8 ha = *(const bf16x8*)&arow[k0];
        bf16x8 am;
#pragma unroll
        for (int j = 0; j < 8; j++) {
            float fv = fmaf(bf2f(ha[j]), scL[k0 + j], shL[k0 + j]);
            am[j] = f2bf(fmaxf(fv, 0.f));
        }
#pragma unroll
        for (int n = 0; n < 4; n++) {
            const int col = w * 64 + n * 16 + il;
            bf16x8 bm = *(const bf16x8*)&W2b[(size_t)col * LAT + k0];
            acc3[n] = __builtin_amdgcn_mfma_f32_16x16x32_bf16(am, bm, acc3[n], 0, 0, 0);
        }
    }
#pragma unroll
    for (int n = 0; n < 4; n++) {
        const int col = w * 64 + n * 16 + il;
        const float bias = b2[col];
#pragma unroll
        for (int r = 0; r < 4; r++) {
            float v = fmaxf(acc3[n][r] + bias, 0.f);
            fLDS[(q * 4 + r) * FPITCH + col] = f2bf(v);
        }
    }
    __syncthreads();

    // ---- GEMM2: out_tile = f_tile @ Wfc^T, cols w*32..+32 ----
    f32x4 acc4[2];
    acc4[0] = (f32x4){0.f,0.f,0.f,0.f};
    acc4[1] = (f32x4){0.f,0.f,0.f,0.f};
#pragma unroll
    for (int ks = 0; ks < 8; ks++) {
        const int k0 = ks * 32 + q * 8;
        bf16x8 am = *(const bf16x8*)&fLDS[il * FPITCH + k0];
#pragma unroll
        for (int n = 0; n < 2; n++) {
            const int col = w * 32 + n * 16 + il;      // padded rows are zero
            bf16x8 bm = *(const bf16x8*)&Wfcb[(size_t)col * Aa + k0];
            acc4[n] = __builtin_amdgcn_mfma_f32_16x16x32_bf16(am, bm, acc4[n], 0, 0, 0);
        }
    }

    const float coef = 0.5f * ratio[0];
    const int4 yv4 = *(const int4*)&y[row0 + q * 4];
    const int yr[4] = {yv4.x, yv4.y, yv4.z, yv4.w};

#pragma unroll
    for (int n = 0; n < 2; n++) {
        const int col = w * 32 + n * 16 + il;
        if (col < Cc) {
            const float bias = bfc[col];
#pragma unroll
            for (int r = 0; r < 4; r++) {
                const float* sp = &Spart[yr[r] * Cc + col];
                float sv = sp[0] + sp[Cc * Cc];
                out[(size_t)(row0 + q * 4 + r) * Cc + col] =
                    acc4[n][r] + bias + coef * sv;
            }
        }
    }
}

extern "C" void kernel_launch(void* const* d_in, const int* in_sizes, int n_in,
                              void* d_out, int out_size, void* d_ws, size_t ws_size,
                              hipStream_t stream)
{
    const float* s     = (const float*)d_in[0];
    const int*   y     = (const int*)  d_in[1];
    const float* ratio = (const float*)d_in[2];
    const float* W1    = (const float*)d_in[3];
    const float* b1    = (const float*)d_in[4];
    const float* gamma = (const float*)d_in[5];
    const float* beta  = (const float*)d_in[6];
    const float* W2    = (const float*)d_in[7];
    const float* b2    = (const float*)d_in[8];
    const float* Wfc   = (const float*)d_in[9];
    const float* bfc   = (const float*)d_in[10];
    const float* cov   = (const float*)d_in[11];
    float* out = (float*)d_out;
    float* ws  = (float*)d_ws;

    short* hB    = (short*)(ws + OFF_HB);
    float* sums  = ws + OFF_SUMS;
    float* Spart = ws + OFF_SP;
    short* W2b   = (short*)(ws + OFF_W2B);
    short* Wfcb  = (short*)(ws + OFF_WFB);

    hipLaunchKernelGGL(kA, dim3(530), dim3(256), 0, stream,
                       s, W1, b1, Wfc, W2, cov, hB, sums, Spart, W2b, Wfcb);
    hipLaunchKernelGGL(kB, dim3(128), dim3(256), 0, stream,
                       hB, sums, gamma, beta, W2b, b2, Wfcb, bfc, Spart, y, ratio, out);
}